// Round 15
// baseline (272.619 us; speedup 1.0000x reference)
//
#include <hip/hip_runtime.h>
#include <hip/hip_bf16.h>

#define M_NODES 100000
#define N_EDGES 1600000
#define NPAD 100352   // padded node stride
#define SCAN_NB 98    // ceil(100000 / 1024)
#define GB 1563       // gemm blocks: ceil(100000/64); also edge-slice owner blocks

typedef __attribute__((ext_vector_type(8))) short short8;
typedef __attribute__((ext_vector_type(4))) float f32x4;
typedef __attribute__((ext_vector_type(2))) float f32x2;
typedef __attribute__((address_space(3))) void lds_t;
typedef const __attribute__((address_space(1))) void gld_t;

__device__ __forceinline__ ushort f2bf(float f) {
    union { float f; uint u; } x; x.f = f;
    uint r = x.u + 0x7fffu + ((x.u >> 16) & 1u);   // RNE
    return (ushort)(r >> 16);
}
__device__ __forceinline__ float bflo(uint v) {
    union { uint u; float f; } x; x.u = v << 16; return x.f;
}
__device__ __forceinline__ float bfhi(uint v) {
    union { uint u; float f; } x; x.u = v & 0xffff0000u; return x.f;
}

// ---------------------------------------------------------------------------
// weight prep (transpose + bf16), tiny standalone
// ---------------------------------------------------------------------------
__global__ void __launch_bounds__(256)
k_prep(const float* __restrict__ W_in, const float* __restrict__ W_c0,
       const float* __restrict__ W_c1, ushort* __restrict__ Wt_in,
       ushort* __restrict__ Wt_c0, ushort* __restrict__ Wt_c1) {
    const int b = blockIdx.x, t = threadIdx.x;
    if (b < 128) {
        int i = b * 256 + t;              // c = i>>8, k = i&255
        Wt_in[i] = f2bf(W_in[(size_t)(i & 255) * 128 + (i >> 8)]);
    } else if (b < 192) {
        int i = (b - 128) * 256 + t;      // c = i>>7, k = i&127
        Wt_c0[i] = f2bf(W_c0[(size_t)(i & 127) * 128 + (i >> 7)]);
    } else {
        int i = (b - 192) * 256 + t;
        Wt_c1[i] = f2bf(W_c1[(size_t)(i & 127) * 128 + (i >> 7)]);
    }
}

// ---------------------------------------------------------------------------
// scan phase A: per-block (1024-node chunk) raw sum over 8 count replicas
// ---------------------------------------------------------------------------
__global__ void __launch_bounds__(256)
k_scanA(const int* __restrict__ cnt8, int* __restrict__ bsum) {
    __shared__ int sh[256];
    const int b = blockIdx.x, t = threadIdx.x;
    int base = b * 1024 + t * 4;
    int s = 0;
#pragma unroll
    for (int j = 0; j < 4; ++j) {
        int i = base + j;
        if (i < M_NODES) {
#pragma unroll
            for (int r = 0; r < 8; ++r) s += cnt8[r * NPAD + i];
        }
    }
    sh[t] = s;
    __syncthreads();
    for (int o = 128; o; o >>= 1) {
        if (t < o) sh[t] += sh[t + o];
        __syncthreads();
    }
    if (t == 0) bsum[b] = sh[0];
}

// ---------------------------------------------------------------------------
// scan phase C: bsum prefix (uniform) + in-block exclusive scan.
// Emits off, dinv, and PER-REPLICA node offsets offr[r][i].
// ---------------------------------------------------------------------------
__global__ void __launch_bounds__(256)
k_scanC(const int* __restrict__ cnt8, const int* __restrict__ bsum,
        int* __restrict__ off, int* __restrict__ offr, float* __restrict__ dinv) {
    __shared__ int sh[256];
    const int b = blockIdx.x, t = threadIdx.x;

    int pre = 0;                       // exclusive prefix of block sums (uniform)
    for (int j = 0; j < b; ++j) pre += bsum[j];

    int base = b * 1024 + t * 4;
    int loc[4][8];
    int tot[4];
    int s = 0;
#pragma unroll
    for (int j = 0; j < 4; ++j) {
        int i = base + j;
        tot[j] = 0;
#pragma unroll
        for (int r = 0; r < 8; ++r) {
            loc[j][r] = (i < M_NODES) ? cnt8[r * NPAD + i] : 0;
            tot[j] += loc[j][r];
        }
        s += tot[j];
    }
    sh[t] = s;
    __syncthreads();
    for (int o = 1; o < 256; o <<= 1) {
        int u = (t >= o) ? sh[t - o] : 0;
        __syncthreads();
        sh[t] += u;
        __syncthreads();
    }
    int run = pre + sh[t] - s;
#pragma unroll
    for (int j = 0; j < 4; ++j) {
        int i = base + j;
        if (i < M_NODES) {
            off[i] = run;
            dinv[i] = rsqrtf((float)(tot[j] + 1));
            int acc = run;
#pragma unroll
            for (int r = 0; r < 8; ++r) {
                offr[r * NPAD + i] = acc;
                acc += loc[j][r];
            }
            run += tot[j];
        }
    }
    if (b == 0 && t == 0) off[M_NODES] = N_EDGES;
}

// ---------------------------------------------------------------------------
// MFMA GEMM body: A[M,K] @ B[K,128], Bt[128][K] bf16.
// 64x128 tile, BK=64, 4 waves (2x2): wave = 32 rows x 64 cols, 2x4 frags.
// MODE 0: out = bf16(relu(A@B + bias));  MODE 1: out = bf16((A@B)*dinv[row])
// ---------------------------------------------------------------------------
template <int K, int MODE, bool AF32>
__device__ __forceinline__ void
gemm_body(int bid, const void* __restrict__ Av, const ushort* __restrict__ Bt,
          const float* __restrict__ bias, const float* __restrict__ dinv,
          ushort* __restrict__ out) {
    __shared__ ushort As[64 * 64];    // [row][k] 8 KB
    __shared__ ushort Bs[128 * 64];   // [col][k] 16 KB
    const int t = threadIdx.x;
    const int lane = t & 63, w = t >> 6;
    const int wr = w >> 1, wc = w & 1;
    const int l15 = lane & 15, l4 = lane >> 4;
    const int row0 = bid * 64;

    f32x4 acc[2][4] = {};

    for (int k0 = 0; k0 < K; k0 += 64) {
#pragma unroll
        for (int i = 0; i < 4; ++i) {
            int idx = (i * 256 + t) * 8;          // bf16 elem index in tile
            int col = idx >> 6, kc = idx & 63;
            __builtin_amdgcn_global_load_lds(
                (gld_t*)(Bt + (size_t)col * K + k0 + kc),
                (lds_t*)(Bs + idx), 16, 0, 0);
        }
        if (AF32) {
            const float* A = (const float*)Av;
#pragma unroll
            for (int i = 0; i < 2; ++i) {
                int idx = (i * 256 + t) * 8;
                int r = idx >> 6, c = idx & 63;
                int gr = row0 + r; gr = gr < M_NODES ? gr : M_NODES - 1;
                const float4* gp = (const float4*)(A + (size_t)gr * K + k0 + c);
                float4 v0 = gp[0], v1 = gp[1];
                short8 p;
                p[0] = (short)f2bf(v0.x); p[1] = (short)f2bf(v0.y);
                p[2] = (short)f2bf(v0.z); p[3] = (short)f2bf(v0.w);
                p[4] = (short)f2bf(v1.x); p[5] = (short)f2bf(v1.y);
                p[6] = (short)f2bf(v1.z); p[7] = (short)f2bf(v1.w);
                *reinterpret_cast<short8*>(&As[idx]) = p;
            }
        } else {
            const ushort* A = (const ushort*)Av;
#pragma unroll
            for (int i = 0; i < 2; ++i) {
                int idx = (i * 256 + t) * 8;
                int r = idx >> 6, c = idx & 63;
                int gr = row0 + r; gr = gr < M_NODES ? gr : M_NODES - 1;
                __builtin_amdgcn_global_load_lds(
                    (gld_t*)(A + (size_t)gr * K + k0 + c),
                    (lds_t*)(As + idx), 16, 0, 0);
            }
        }
        __syncthreads();
#pragma unroll
        for (int kk = 0; kk < 2; ++kk) {
            short8 af[2], bw[4];
#pragma unroll
            for (int m = 0; m < 2; ++m)
                af[m] = *reinterpret_cast<const short8*>(
                    &As[(wr * 32 + m * 16 + l15) * 64 + kk * 32 + l4 * 8]);
#pragma unroll
            for (int n = 0; n < 4; ++n)
                bw[n] = *reinterpret_cast<const short8*>(
                    &Bs[(wc * 64 + n * 16 + l15) * 64 + kk * 32 + l4 * 8]);
#pragma unroll
            for (int m = 0; m < 2; ++m)
#pragma unroll
                for (int n = 0; n < 4; ++n)
                    acc[m][n] = __builtin_amdgcn_mfma_f32_16x16x32_bf16(
                        af[m], bw[n], acc[m][n], 0, 0, 0);
        }
        __syncthreads();
    }

    // epilogue: C[row][col], col = lane&15, row = (lane>>4)*4 + j
#pragma unroll
    for (int m = 0; m < 2; ++m) {
#pragma unroll
        for (int j = 0; j < 4; ++j) {
            int r = row0 + wr * 32 + m * 16 + l4 * 4 + j;
            if (r < M_NODES) {
                float sc = (MODE == 1) ? dinv[r] : 0.f;
#pragma unroll
                for (int n = 0; n < 4; ++n) {
                    int c = wc * 64 + n * 16 + l15;
                    float v = acc[m][n][j];
                    if (MODE == 0) v = fmaxf(v + bias[c], 0.f);
                    else v *= sc;
                    out[(size_t)r * 128 + c] = f2bf(v);
                }
            }
        }
    }
}

// ---------------------------------------------------------------------------
// edge-slice helpers (4 edges/thread per block slice; GB*1024 >= N_EDGES)
// count: 8-way replicated counters — block uses replica (bid>>1)&7 so both
// stagger parities spread across all replicas. rank packs replica<<13 | lr.
// ---------------------------------------------------------------------------
__device__ __forceinline__ void
count_slice(int bid, const int* __restrict__ dst, int* __restrict__ cnt8,
            ushort* __restrict__ rank) {
    const int rep = (bid >> 1) & 7;
    int* mycnt = cnt8 + rep * NPAD;
    const int base = bid * 1024 + threadIdx.x;
    int d[4]; bool ok[4]; int r[4];
#pragma unroll
    for (int i = 0; i < 4; ++i) {
        int e = base + i * 256;
        ok[i] = e < N_EDGES;
        d[i] = ok[i] ? dst[e] : 0;
    }
#pragma unroll
    for (int i = 0; i < 4; ++i)
        if (ok[i]) r[i] = atomicAdd(&mycnt[d[i]], 1);
#pragma unroll
    for (int i = 0; i < 4; ++i)
        if (ok[i]) rank[base + i * 256] = (ushort)(r[i] | (rep << 13));
}

__device__ __forceinline__ void
fill_slice(int bid, const int* __restrict__ src, const int* __restrict__ dst,
           const int* __restrict__ offr, const ushort* __restrict__ rank,
           int* __restrict__ csr) {
    const int base = bid * 1024 + threadIdx.x;
    int d[4], s[4]; ushort r[4]; bool ok[4]; int o[4];
#pragma unroll
    for (int i = 0; i < 4; ++i) {
        int e = base + i * 256;
        ok[i] = e < N_EDGES;
        d[i] = ok[i] ? dst[e] : 0;
        s[i] = ok[i] ? src[e] : 0;
        r[i] = ok[i] ? rank[e] : 0;
    }
#pragma unroll
    for (int i = 0; i < 4; ++i)
        o[i] = ok[i] ? offr[(r[i] >> 13) * NPAD + d[i]] + (int)(r[i] & 8191) : 0;
#pragma unroll
    for (int i = 0; i < 4; ++i)
        if (ok[i]) csr[o[i]] = s[i];
}

// ---------------------------------------------------------------------------
// phase 1: input GEMM + count+rank slice, staggered by block parity
// ---------------------------------------------------------------------------
__global__ void __launch_bounds__(256)
k_phase1(const float* __restrict__ x, const ushort* __restrict__ Wt_in,
         const float* __restrict__ b_in, ushort* __restrict__ h,
         const int* __restrict__ dst, int* __restrict__ cnt8,
         ushort* __restrict__ rank) {
    if (blockIdx.x & 1) {
        count_slice(blockIdx.x, dst, cnt8, rank);
        gemm_body<256, 0, true>(blockIdx.x, x, Wt_in, b_in, nullptr, h);
    } else {
        gemm_body<256, 0, true>(blockIdx.x, x, Wt_in, b_in, nullptr, h);
        count_slice(blockIdx.x, dst, cnt8, rank);
    }
}

// ---------------------------------------------------------------------------
// phase 3: conv0 GEMM + atomic-free CSR fill slice, same stagger
// ---------------------------------------------------------------------------
__global__ void __launch_bounds__(256)
k_phase3(const ushort* __restrict__ h, const ushort* __restrict__ Wt_c0,
         const float* __restrict__ dinv, ushort* __restrict__ hs,
         const int* __restrict__ src, const int* __restrict__ dst,
         const int* __restrict__ offr, const ushort* __restrict__ rank,
         int* __restrict__ csr) {
    if (blockIdx.x & 1) {
        fill_slice(blockIdx.x, src, dst, offr, rank, csr);
        gemm_body<128, 1, false>(blockIdx.x, h, Wt_c0, nullptr, dinv, hs);
    } else {
        gemm_body<128, 1, false>(blockIdx.x, h, Wt_c0, nullptr, dinv, hs);
        fill_slice(blockIdx.x, src, dst, offr, rank, csr);
    }
}

template <int K, int MODE, bool AF32>
__global__ void __launch_bounds__(256)
k_gemm(const void* __restrict__ Av, const ushort* __restrict__ Bt,
       const float* __restrict__ bias, const float* __restrict__ dinv,
       ushort* __restrict__ out) {
    gemm_body<K, MODE, AF32>(blockIdx.x, Av, Bt, bias, dinv, out);
}

// ---------------------------------------------------------------------------
// HALF-WAVE neighbor accumulation: 32 lanes per node, lane loads uint2 (8B)
// -> one wave-wide load = 512B for TWO nodes; 8-deep chains per half.
// ---------------------------------------------------------------------------
__device__ __forceinline__ f32x4
gather_accum_hw(const char* __restrict__ hs_bytes, const int* __restrict__ csr,
                int beg, int end, int l5) {
    f32x4 acc0 = {}, acc1 = {}, acc2 = {}, acc3 = {};
    const int halfb4 = (threadIdx.x & 32) * 4;   // bpermute byte-index base of own half
    const int myoff = l5 * 8;                    // byte offset within 256B row
    for (int b = beg; b < end; b += 32) {
        int m = end - b; if (m > 32) m = 32;
        int idx = (l5 < m) ? csr[b + l5] : 0;
        int rowoff = idx << 8;                   // byte offset of neighbor row
        for (int i = 0; i < m; i += 8) {
            uint2 v0, v1, v2, v3, v4, v5, v6, v7;
            {
                int r0 = __builtin_amdgcn_ds_bpermute(halfb4 + (i + 0) * 4, rowoff);
                int r1 = __builtin_amdgcn_ds_bpermute(halfb4 + (i + 1) * 4, rowoff);
                int r2 = __builtin_amdgcn_ds_bpermute(halfb4 + (i + 2) * 4, rowoff);
                int r3 = __builtin_amdgcn_ds_bpermute(halfb4 + (i + 3) * 4, rowoff);
                int r4 = __builtin_amdgcn_ds_bpermute(halfb4 + (i + 4) * 4, rowoff);
                int r5 = __builtin_amdgcn_ds_bpermute(halfb4 + (i + 5) * 4, rowoff);
                int r6 = __builtin_amdgcn_ds_bpermute(halfb4 + (i + 6) * 4, rowoff);
                int r7 = __builtin_amdgcn_ds_bpermute(halfb4 + (i + 7) * 4, rowoff);
                v0 = *(const uint2*)(hs_bytes + (uint)(r0 + myoff));
                v1 = *(const uint2*)(hs_bytes + (uint)(r1 + myoff));
                v2 = *(const uint2*)(hs_bytes + (uint)(r2 + myoff));
                v3 = *(const uint2*)(hs_bytes + (uint)(r3 + myoff));
                v4 = *(const uint2*)(hs_bytes + (uint)(r4 + myoff));
                v5 = *(const uint2*)(hs_bytes + (uint)(r5 + myoff));
                v6 = *(const uint2*)(hs_bytes + (uint)(r6 + myoff));
                v7 = *(const uint2*)(hs_bytes + (uint)(r7 + myoff));
            }
            if (i + 0 < m) acc0 += (f32x4){bflo(v0.x), bfhi(v0.x), bflo(v0.y), bfhi(v0.y)};
            if (i + 1 < m) acc1 += (f32x4){bflo(v1.x), bfhi(v1.x), bflo(v1.y), bfhi(v1.y)};
            if (i + 2 < m) acc2 += (f32x4){bflo(v2.x), bfhi(v2.x), bflo(v2.y), bfhi(v2.y)};
            if (i + 3 < m) acc3 += (f32x4){bflo(v3.x), bfhi(v3.x), bflo(v3.y), bfhi(v3.y)};
            if (i + 4 < m) acc0 += (f32x4){bflo(v4.x), bfhi(v4.x), bflo(v4.y), bfhi(v4.y)};
            if (i + 5 < m) acc1 += (f32x4){bflo(v5.x), bfhi(v5.x), bflo(v5.y), bfhi(v5.y)};
            if (i + 6 < m) acc2 += (f32x4){bflo(v6.x), bfhi(v6.x), bflo(v6.y), bfhi(v6.y)};
            if (i + 7 < m) acc3 += (f32x4){bflo(v7.x), bfhi(v7.x), bflo(v7.y), bfhi(v7.y)};
        }
    }
    return (acc0 + acc1) + (acc2 + acc3);
}

// ---------------------------------------------------------------------------
// gather-aggregate (bf16), half-wave: 8 nodes per 256-thr block
// ---------------------------------------------------------------------------
__global__ void __launch_bounds__(256)
k_gather(const ushort* __restrict__ hs, const int* __restrict__ csr,
         const int* __restrict__ off, const float* __restrict__ dinv,
         const float* __restrict__ bias, ushort* __restrict__ out) {
    const int l5 = threadIdx.x & 31;
    const int n = blockIdx.x * 8 + (threadIdx.x >> 5);   // 100000 = 12500*8

    const char* hsb = (const char*)hs;
    const int myoff = l5 * 8;
    int beg = off[n], end = off[n + 1];
    float di = dinv[n];
    uint2 self = *(const uint2*)(hsb + ((size_t)n << 8) + myoff);

    f32x4 s = gather_accum_hw(hsb, csr, beg, end, l5);
    s += (f32x4){bflo(self.x), bfhi(self.x), bflo(self.y), bfhi(self.y)};

    float4 bb = ((const float4*)bias)[l5];
    uint rx = (uint)f2bf(fmaxf(fmaf(s.x, di, bb.x), 0.f)) |
              ((uint)f2bf(fmaxf(fmaf(s.y, di, bb.y), 0.f)) << 16);
    uint ry = (uint)f2bf(fmaxf(fmaf(s.z, di, bb.z), 0.f)) |
              ((uint)f2bf(fmaxf(fmaf(s.w, di, bb.w), 0.f)) << 16);
    *(uint2*)((char*)out + ((size_t)n << 8) + myoff) = (uint2){rx, ry};
}

// ---------------------------------------------------------------------------
// gather1 + output head fused, half-wave; head rows issued early.
// ---------------------------------------------------------------------------
__global__ void __launch_bounds__(256)
k_gather_out(const ushort* __restrict__ hs, const int* __restrict__ csr,
             const int* __restrict__ off, const float* __restrict__ dinv,
             const float* __restrict__ bias, const ushort* __restrict__ h,
             const ushort* __restrict__ c0, const float* __restrict__ Wout,
             const float* __restrict__ bout, float* __restrict__ out) {
    const int l5 = threadIdx.x & 31;
    const int n = blockIdx.x * 8 + (threadIdx.x >> 5);

    const char* hsb = (const char*)hs;
    const int myoff = l5 * 8;
    size_t rowb = (size_t)n << 8;
    // issue early: self + head rows + head weights
    uint2 self = *(const uint2*)(hsb + rowb + myoff);
    uint2 a  = *(const uint2*)((const char*)h + rowb + myoff);
    uint2 b2 = *(const uint2*)((const char*)c0 + rowb + myoff);
    float4 wh = ((const float4*)Wout)[l5];
    float4 w0 = ((const float4*)(Wout + 128))[l5];
    float4 w1 = ((const float4*)(Wout + 256))[l5];
    int beg = off[n], end = off[n + 1];
    float di = dinv[n];

    f32x4 s = gather_accum_hw(hsb, csr, beg, end, l5);
    s += (f32x4){bflo(self.x), bfhi(self.x), bflo(self.y), bfhi(self.y)};

    float4 bb = ((const float4*)bias)[l5];
    float cx = fmaxf(fmaf(s.x, di, bb.x), 0.f);   // c1 chans (fp32)
    float cy = fmaxf(fmaf(s.y, di, bb.y), 0.f);
    float cz = fmaxf(fmaf(s.z, di, bb.z), 0.f);
    float cw = fmaxf(fmaf(s.w, di, bb.w), 0.f);

    float v = bflo(a.x) * wh.x + bfhi(a.x) * wh.y +
              bflo(a.y) * wh.z + bfhi(a.y) * wh.w +
              bflo(b2.x) * w0.x + bfhi(b2.x) * w0.y +
              bflo(b2.y) * w0.z + bfhi(b2.y) * w0.w +
              cx * w1.x + cy * w1.y + cz * w1.z + cw * w1.w;
#pragma unroll
    for (int o = 16; o; o >>= 1) v += __shfl_xor(v, o);  // stays within half
    if (l5 == 0) out[n] = v + bout[0];
}

// ---------------------------------------------------------------------------
extern "C" void kernel_launch(void* const* d_in, const int* in_sizes, int n_in,
                              void* d_out, int out_size, void* d_ws, size_t ws_size,
                              hipStream_t stream) {
    const float* x     = (const float*)d_in[0];
    const int*   eidx  = (const int*)d_in[1];
    const float* W_in  = (const float*)d_in[2];
    const float* b_in  = (const float*)d_in[3];
    const float* W_c0  = (const float*)d_in[4];
    const float* b_c0  = (const float*)d_in[5];
    const float* W_c1  = (const float*)d_in[6];
    const float* b_c1  = (const float*)d_in[7];
    const float* W_out = (const float*)d_in[8];
    const float* b_out = (const float*)d_in[9];
    float* out = (float*)d_out;

    const int* src = eidx;
    const int* dst = eidx + N_EDGES;

    // workspace layout (4-byte units)
    float*  ws     = (float*)d_ws;
    float*  dinv   = ws;                            // 100352
    int*    cnt8   = (int*)(ws + 100352);           // 8*100352 = 802816
    int*    off    = (int*)(ws + 903168);           // 100352 (N+1 used)
    int*    offr   = (int*)(ws + 1003520);          // 8*100352 = 802816
    int*    bsum   = (int*)(ws + 1806336);          // 128
    int*    csr    = (int*)(ws + 1806464);          // 1600000
    ushort* Wt_in  = (ushort*)(ws + 3406464);       // 32768 bf16
    ushort* Wt_c0  = (ushort*)(ws + 3422848);       // 16384 bf16
    ushort* Wt_c1  = (ushort*)(ws + 3431040);       // 16384 bf16
    ushort* h      = (ushort*)(ws + 3439232);       // 12.8M bf16
    ushort* c0     = (ushort*)(ws + 9839232);
    ushort* rank   = (ushort*)(ws + 16239232);      // 1.6M
    ushort* hs     = (ushort*)(ws + 17039232);

    // zero the 8 replicated degree-counter arrays
    hipMemsetAsync(cnt8, 0, 8 * NPAD * sizeof(int), stream);

    // weight prep (tiny; must precede phase1 which consumes Wt_in)
    k_prep<<<256, 256, 0, stream>>>(W_in, W_c0, W_c1, Wt_in, Wt_c0, Wt_c1);

    // phase 1: input GEMM || count+rank (block-parity staggered, 8-way replicas)
    k_phase1<<<GB, 256, 0, stream>>>(x, Wt_in, b_in, h, dst, cnt8, rank);

    // scan: cnt8 -> off, offr, dinv
    k_scanA<<<SCAN_NB, 256, 0, stream>>>(cnt8, bsum);
    k_scanC<<<SCAN_NB, 256, 0, stream>>>(cnt8, bsum, off, offr, dinv);

    // phase 3: conv0 GEMM || CSR fill (block-parity staggered, offr-based)
    k_phase3<<<GB, 256, 0, stream>>>(h, Wt_c0, dinv, hs, src, dst, offr, rank, csr);

    // conv0 aggregate (half-wave, 8 nodes/block)
    k_gather<<<M_NODES / 8, 256, 0, stream>>>(hs, csr, off, dinv, b_c0, c0);

    // conv1 GEMM
    k_gemm<128, 1, false><<<GB, 256, 0, stream>>>(c0, Wt_c1, nullptr, dinv, hs);

    // conv1 aggregate + output head (fused, half-wave)
    k_gather_out<<<M_NODES / 8, 256, 0, stream>>>(hs, csr, off, dinv, b_c1,
                                                  h, c0, W_out, b_out, out);
}

// Round 16
// 261.285 us; speedup vs baseline: 1.0434x; 1.0434x over previous
//
#include <hip/hip_runtime.h>
#include <hip/hip_bf16.h>

#define M_NODES 100000
#define N_EDGES 1600000
#define SCAN_NB 98    // ceil(100000 / 1024)
#define GB 1563       // gemm blocks: ceil(100000/64); also edge-slice owner blocks

typedef __attribute__((ext_vector_type(8))) short short8;
typedef __attribute__((ext_vector_type(4))) float f32x4;
typedef __attribute__((ext_vector_type(2))) float f32x2;
typedef __attribute__((address_space(3))) void lds_t;
typedef const __attribute__((address_space(1))) void gld_t;

__device__ __forceinline__ ushort f2bf(float f) {
    union { float f; uint u; } x; x.f = f;
    uint r = x.u + 0x7fffu + ((x.u >> 16) & 1u);   // RNE
    return (ushort)(r >> 16);
}
__device__ __forceinline__ float bflo(uint v) {
    union { uint u; float f; } x; x.u = v << 16; return x.f;
}
__device__ __forceinline__ float bfhi(uint v) {
    union { uint u; float f; } x; x.u = v & 0xffff0000u; return x.f;
}

// ---------------------------------------------------------------------------
// weight prep (transpose + bf16) + cnt zeroing (replaces memset dispatch)
// blocks 0..127: Wt_in; 128..191: Wt_c0; 192..255: Wt_c1; 256..353: zero cnt
// ---------------------------------------------------------------------------
__global__ void __launch_bounds__(256)
k_prep(const float* __restrict__ W_in, const float* __restrict__ W_c0,
       const float* __restrict__ W_c1, ushort* __restrict__ Wt_in,
       ushort* __restrict__ Wt_c0, ushort* __restrict__ Wt_c1,
       int* __restrict__ cnt) {
    const int b = blockIdx.x, t = threadIdx.x;
    if (b < 128) {
        int i = b * 256 + t;              // c = i>>8, k = i&255
        Wt_in[i] = f2bf(W_in[(size_t)(i & 255) * 128 + (i >> 8)]);
    } else if (b < 192) {
        int i = (b - 128) * 256 + t;      // c = i>>7, k = i&127
        Wt_c0[i] = f2bf(W_c0[(size_t)(i & 127) * 128 + (i >> 7)]);
    } else if (b < 256) {
        int i = (b - 192) * 256 + t;
        Wt_c1[i] = f2bf(W_c1[(size_t)(i & 127) * 128 + (i >> 7)]);
    } else {
        int base = (b - 256) * 1024 + t * 4;
#pragma unroll
        for (int j = 0; j < 4; ++j)
            if (base + j < M_NODES) cnt[base + j] = 0;
    }
}

// ---------------------------------------------------------------------------
// scan phase A: per-block (1024-node chunk) raw sum
// ---------------------------------------------------------------------------
__global__ void __launch_bounds__(256)
k_scanA(const int* __restrict__ cnt, int* __restrict__ bsum) {
    __shared__ int sh[256];
    const int b = blockIdx.x, t = threadIdx.x;
    int base = b * 1024 + t * 4;
    int s = 0;
#pragma unroll
    for (int j = 0; j < 4; ++j) {
        int i = base + j;
        if (i < M_NODES) s += cnt[i];
    }
    sh[t] = s;
    __syncthreads();
    for (int o = 128; o; o >>= 1) {
        if (t < o) sh[t] += sh[t + o];
        __syncthreads();
    }
    if (t == 0) bsum[b] = sh[0];
}

// ---------------------------------------------------------------------------
// scan phase C (merged with B): each block scalar-sums its bsum prefix,
// then in-block exclusive scan -> off/dinv.
// ---------------------------------------------------------------------------
__global__ void __launch_bounds__(256)
k_scanC(const int* __restrict__ cnt, const int* __restrict__ bsum,
        int* __restrict__ off, float* __restrict__ dinv) {
    __shared__ int sh[256];
    const int b = blockIdx.x, t = threadIdx.x;

    int pre = 0;                       // exclusive prefix of block sums (uniform)
    for (int j = 0; j < b; ++j) pre += bsum[j];

    int base = b * 1024 + t * 4;
    int loc[4];
    int s = 0;
#pragma unroll
    for (int j = 0; j < 4; ++j) {
        int i = base + j;
        loc[j] = (i < M_NODES) ? cnt[i] : 0;
        s += loc[j];
    }
    sh[t] = s;
    __syncthreads();
    for (int o = 1; o < 256; o <<= 1) {
        int u = (t >= o) ? sh[t - o] : 0;
        __syncthreads();
        sh[t] += u;
        __syncthreads();
    }
    int run = pre + sh[t] - s;
#pragma unroll
    for (int j = 0; j < 4; ++j) {
        int i = base + j;
        if (i < M_NODES) {
            off[i] = run;
            dinv[i] = rsqrtf((float)(loc[j] + 1));
            run += loc[j];
        }
    }
    if (b == 0 && t == 0) off[M_NODES] = N_EDGES;
}

// ---------------------------------------------------------------------------
// MFMA GEMM body: A[M,K] @ B[K,128], Bt[128][K] bf16.
// 64x128 tile, BK=64, 4 waves (2x2): wave = 32 rows x 64 cols, 2x4 frags.
// MODE 0: out = bf16(relu(A@B + bias));  MODE 1: out = bf16((A@B)*dinv[row])
// ---------------------------------------------------------------------------
template <int K, int MODE, bool AF32>
__device__ __forceinline__ void
gemm_body(int bid, const void* __restrict__ Av, const ushort* __restrict__ Bt,
          const float* __restrict__ bias, const float* __restrict__ dinv,
          ushort* __restrict__ out) {
    __shared__ ushort As[64 * 64];    // [row][k] 8 KB
    __shared__ ushort Bs[128 * 64];   // [col][k] 16 KB
    const int t = threadIdx.x;
    const int lane = t & 63, w = t >> 6;
    const int wr = w >> 1, wc = w & 1;
    const int l15 = lane & 15, l4 = lane >> 4;
    const int row0 = bid * 64;

    f32x4 acc[2][4] = {};

    for (int k0 = 0; k0 < K; k0 += 64) {
#pragma unroll
        for (int i = 0; i < 4; ++i) {
            int idx = (i * 256 + t) * 8;          // bf16 elem index in tile
            int col = idx >> 6, kc = idx & 63;
            __builtin_amdgcn_global_load_lds(
                (gld_t*)(Bt + (size_t)col * K + k0 + kc),
                (lds_t*)(Bs + idx), 16, 0, 0);
        }
        if (AF32) {
            const float* A = (const float*)Av;
#pragma unroll
            for (int i = 0; i < 2; ++i) {
                int idx = (i * 256 + t) * 8;
                int r = idx >> 6, c = idx & 63;
                int gr = row0 + r; gr = gr < M_NODES ? gr : M_NODES - 1;
                const float4* gp = (const float4*)(A + (size_t)gr * K + k0 + c);
                float4 v0 = gp[0], v1 = gp[1];
                short8 p;
                p[0] = (short)f2bf(v0.x); p[1] = (short)f2bf(v0.y);
                p[2] = (short)f2bf(v0.z); p[3] = (short)f2bf(v0.w);
                p[4] = (short)f2bf(v1.x); p[5] = (short)f2bf(v1.y);
                p[6] = (short)f2bf(v1.z); p[7] = (short)f2bf(v1.w);
                *reinterpret_cast<short8*>(&As[idx]) = p;
            }
        } else {
            const ushort* A = (const ushort*)Av;
#pragma unroll
            for (int i = 0; i < 2; ++i) {
                int idx = (i * 256 + t) * 8;
                int r = idx >> 6, c = idx & 63;
                int gr = row0 + r; gr = gr < M_NODES ? gr : M_NODES - 1;
                __builtin_amdgcn_global_load_lds(
                    (gld_t*)(A + (size_t)gr * K + k0 + c),
                    (lds_t*)(As + idx), 16, 0, 0);
            }
        }
        __syncthreads();
#pragma unroll
        for (int kk = 0; kk < 2; ++kk) {
            short8 af[2], bw[4];
#pragma unroll
            for (int m = 0; m < 2; ++m)
                af[m] = *reinterpret_cast<const short8*>(
                    &As[(wr * 32 + m * 16 + l15) * 64 + kk * 32 + l4 * 8]);
#pragma unroll
            for (int n = 0; n < 4; ++n)
                bw[n] = *reinterpret_cast<const short8*>(
                    &Bs[(wc * 64 + n * 16 + l15) * 64 + kk * 32 + l4 * 8]);
#pragma unroll
            for (int m = 0; m < 2; ++m)
#pragma unroll
                for (int n = 0; n < 4; ++n)
                    acc[m][n] = __builtin_amdgcn_mfma_f32_16x16x32_bf16(
                        af[m], bw[n], acc[m][n], 0, 0, 0);
        }
        __syncthreads();
    }

    // epilogue: C[row][col], col = lane&15, row = (lane>>4)*4 + j
#pragma unroll
    for (int m = 0; m < 2; ++m) {
#pragma unroll
        for (int j = 0; j < 4; ++j) {
            int r = row0 + wr * 32 + m * 16 + l4 * 4 + j;
            if (r < M_NODES) {
                float sc = (MODE == 1) ? dinv[r] : 0.f;
#pragma unroll
                for (int n = 0; n < 4; ++n) {
                    int c = wc * 64 + n * 16 + l15;
                    float v = acc[m][n][j];
                    if (MODE == 0) v = fmaxf(v + bias[c], 0.f);
                    else v *= sc;
                    out[(size_t)r * 128 + c] = f2bf(v);
                }
            }
        }
    }
}

// ---------------------------------------------------------------------------
// edge-slice helpers (4 edges/thread per block slice; GB*1024 >= N_EDGES)
// ---------------------------------------------------------------------------
__device__ __forceinline__ void
count_slice(int bid, const int* __restrict__ dst, int* __restrict__ cnt,
            ushort* __restrict__ rank) {
    const int base = bid * 1024 + threadIdx.x;
    int d[4]; bool ok[4]; int r[4];
#pragma unroll
    for (int i = 0; i < 4; ++i) {
        int e = base + i * 256;
        ok[i] = e < N_EDGES;
        d[i] = ok[i] ? dst[e] : 0;
    }
#pragma unroll
    for (int i = 0; i < 4; ++i)
        if (ok[i]) r[i] = atomicAdd(&cnt[d[i]], 1);
#pragma unroll
    for (int i = 0; i < 4; ++i)
        if (ok[i]) rank[base + i * 256] = (ushort)r[i];
}

__device__ __forceinline__ void
fill_slice(int bid, const int* __restrict__ src, const int* __restrict__ dst,
           const int* __restrict__ off, const ushort* __restrict__ rank,
           int* __restrict__ csr) {
    const int base = bid * 1024 + threadIdx.x;
    int d[4], s[4]; ushort r[4]; bool ok[4]; int o[4];
#pragma unroll
    for (int i = 0; i < 4; ++i) {
        int e = base + i * 256;
        ok[i] = e < N_EDGES;
        d[i] = ok[i] ? dst[e] : 0;
        s[i] = ok[i] ? src[e] : 0;
        r[i] = ok[i] ? rank[e] : 0;
    }
#pragma unroll
    for (int i = 0; i < 4; ++i) o[i] = ok[i] ? off[d[i]] : 0;
#pragma unroll
    for (int i = 0; i < 4; ++i)
        if (ok[i]) csr[o[i] + (int)r[i]] = s[i];
}

// ---------------------------------------------------------------------------
// phase 1: input GEMM + count+rank slice, staggered by block parity
// ---------------------------------------------------------------------------
__global__ void __launch_bounds__(256)
k_phase1(const float* __restrict__ x, const ushort* __restrict__ Wt_in,
         const float* __restrict__ b_in, ushort* __restrict__ h,
         const int* __restrict__ dst, int* __restrict__ cnt,
         ushort* __restrict__ rank) {
    if (blockIdx.x & 1) {
        count_slice(blockIdx.x, dst, cnt, rank);
        gemm_body<256, 0, true>(blockIdx.x, x, Wt_in, b_in, nullptr, h);
    } else {
        gemm_body<256, 0, true>(blockIdx.x, x, Wt_in, b_in, nullptr, h);
        count_slice(blockIdx.x, dst, cnt, rank);
    }
}

// ---------------------------------------------------------------------------
// phase 3: conv0 GEMM + atomic-free CSR fill slice, same stagger
// ---------------------------------------------------------------------------
__global__ void __launch_bounds__(256)
k_phase3(const ushort* __restrict__ h, const ushort* __restrict__ Wt_c0,
         const float* __restrict__ dinv, ushort* __restrict__ hs,
         const int* __restrict__ src, const int* __restrict__ dst,
         const int* __restrict__ off, const ushort* __restrict__ rank,
         int* __restrict__ csr) {
    if (blockIdx.x & 1) {
        fill_slice(blockIdx.x, src, dst, off, rank, csr);
        gemm_body<128, 1, false>(blockIdx.x, h, Wt_c0, nullptr, dinv, hs);
    } else {
        gemm_body<128, 1, false>(blockIdx.x, h, Wt_c0, nullptr, dinv, hs);
        fill_slice(blockIdx.x, src, dst, off, rank, csr);
    }
}

template <int K, int MODE, bool AF32>
__global__ void __launch_bounds__(256)
k_gemm(const void* __restrict__ Av, const ushort* __restrict__ Bt,
       const float* __restrict__ bias, const float* __restrict__ dinv,
       ushort* __restrict__ out) {
    gemm_body<K, MODE, AF32>(blockIdx.x, Av, Bt, bias, dinv, out);
}

// ---------------------------------------------------------------------------
// HALF-WAVE neighbor accumulation: 32 lanes per node, lane loads uint2 (8B)
// -> one wave-wide load = 512B for TWO nodes; 8-deep chains per half.
// ---------------------------------------------------------------------------
__device__ __forceinline__ f32x4
gather_accum_hw(const char* __restrict__ hs_bytes, const int* __restrict__ csr,
                int beg, int end, int l5) {
    f32x4 acc0 = {}, acc1 = {}, acc2 = {}, acc3 = {};
    const int halfb4 = (threadIdx.x & 32) * 4;   // bpermute byte-index base of own half
    const int myoff = l5 * 8;                    // byte offset within 256B row
    for (int b = beg; b < end; b += 32) {
        int m = end - b; if (m > 32) m = 32;
        int idx = (l5 < m) ? csr[b + l5] : 0;
        int rowoff = idx << 8;                   // byte offset of neighbor row
        for (int i = 0; i < m; i += 8) {
            uint2 v0, v1, v2, v3, v4, v5, v6, v7;
            {
                int r0 = __builtin_amdgcn_ds_bpermute(halfb4 + (i + 0) * 4, rowoff);
                int r1 = __builtin_amdgcn_ds_bpermute(halfb4 + (i + 1) * 4, rowoff);
                int r2 = __builtin_amdgcn_ds_bpermute(halfb4 + (i + 2) * 4, rowoff);
                int r3 = __builtin_amdgcn_ds_bpermute(halfb4 + (i + 3) * 4, rowoff);
                int r4 = __builtin_amdgcn_ds_bpermute(halfb4 + (i + 4) * 4, rowoff);
                int r5 = __builtin_amdgcn_ds_bpermute(halfb4 + (i + 5) * 4, rowoff);
                int r6 = __builtin_amdgcn_ds_bpermute(halfb4 + (i + 6) * 4, rowoff);
                int r7 = __builtin_amdgcn_ds_bpermute(halfb4 + (i + 7) * 4, rowoff);
                v0 = *(const uint2*)(hs_bytes + (uint)(r0 + myoff));
                v1 = *(const uint2*)(hs_bytes + (uint)(r1 + myoff));
                v2 = *(const uint2*)(hs_bytes + (uint)(r2 + myoff));
                v3 = *(const uint2*)(hs_bytes + (uint)(r3 + myoff));
                v4 = *(const uint2*)(hs_bytes + (uint)(r4 + myoff));
                v5 = *(const uint2*)(hs_bytes + (uint)(r5 + myoff));
                v6 = *(const uint2*)(hs_bytes + (uint)(r6 + myoff));
                v7 = *(const uint2*)(hs_bytes + (uint)(r7 + myoff));
            }
            if (i + 0 < m) acc0 += (f32x4){bflo(v0.x), bfhi(v0.x), bflo(v0.y), bfhi(v0.y)};
            if (i + 1 < m) acc1 += (f32x4){bflo(v1.x), bfhi(v1.x), bflo(v1.y), bfhi(v1.y)};
            if (i + 2 < m) acc2 += (f32x4){bflo(v2.x), bfhi(v2.x), bflo(v2.y), bfhi(v2.y)};
            if (i + 3 < m) acc3 += (f32x4){bflo(v3.x), bfhi(v3.x), bflo(v3.y), bfhi(v3.y)};
            if (i + 4 < m) acc0 += (f32x4){bflo(v4.x), bfhi(v4.x), bflo(v4.y), bfhi(v4.y)};
            if (i + 5 < m) acc1 += (f32x4){bflo(v5.x), bfhi(v5.x), bflo(v5.y), bfhi(v5.y)};
            if (i + 6 < m) acc2 += (f32x4){bflo(v6.x), bfhi(v6.x), bflo(v6.y), bfhi(v6.y)};
            if (i + 7 < m) acc3 += (f32x4){bflo(v7.x), bfhi(v7.x), bflo(v7.y), bfhi(v7.y)};
        }
    }
    return (acc0 + acc1) + (acc2 + acc3);
}

// ---------------------------------------------------------------------------
// gather-aggregate (bf16), half-wave: 8 nodes per 256-thr block
// ---------------------------------------------------------------------------
__global__ void __launch_bounds__(256)
k_gather(const ushort* __restrict__ hs, const int* __restrict__ csr,
         const int* __restrict__ off, const float* __restrict__ dinv,
         const float* __restrict__ bias, ushort* __restrict__ out) {
    const int l5 = threadIdx.x & 31;
    const int n = blockIdx.x * 8 + (threadIdx.x >> 5);   // 100000 = 12500*8

    const char* hsb = (const char*)hs;
    const int myoff = l5 * 8;
    int beg = off[n], end = off[n + 1];
    float di = dinv[n];
    uint2 self = *(const uint2*)(hsb + ((size_t)n << 8) + myoff);

    f32x4 s = gather_accum_hw(hsb, csr, beg, end, l5);
    s += (f32x4){bflo(self.x), bfhi(self.x), bflo(self.y), bfhi(self.y)};

    float4 bb = ((const float4*)bias)[l5];
    uint rx = (uint)f2bf(fmaxf(fmaf(s.x, di, bb.x), 0.f)) |
              ((uint)f2bf(fmaxf(fmaf(s.y, di, bb.y), 0.f)) << 16);
    uint ry = (uint)f2bf(fmaxf(fmaf(s.z, di, bb.z), 0.f)) |
              ((uint)f2bf(fmaxf(fmaf(s.w, di, bb.w), 0.f)) << 16);
    *(uint2*)((char*)out + ((size_t)n << 8) + myoff) = (uint2){rx, ry};
}

// ---------------------------------------------------------------------------
// gather1 + output head fused, half-wave; head rows issued early.
// ---------------------------------------------------------------------------
__global__ void __launch_bounds__(256)
k_gather_out(const ushort* __restrict__ hs, const int* __restrict__ csr,
             const int* __restrict__ off, const float* __restrict__ dinv,
             const float* __restrict__ bias, const ushort* __restrict__ h,
             const ushort* __restrict__ c0, const float* __restrict__ Wout,
             const float* __restrict__ bout, float* __restrict__ out) {
    const int l5 = threadIdx.x & 31;
    const int n = blockIdx.x * 8 + (threadIdx.x >> 5);

    const char* hsb = (const char*)hs;
    const int myoff = l5 * 8;
    size_t rowb = (size_t)n << 8;
    // issue early: self + head rows + head weights
    uint2 self = *(const uint2*)(hsb + rowb + myoff);
    uint2 a  = *(const uint2*)((const char*)h + rowb + myoff);
    uint2 b2 = *(const uint2*)((const char*)c0 + rowb + myoff);
    float4 wh = ((const float4*)Wout)[l5];
    float4 w0 = ((const float4*)(Wout + 128))[l5];
    float4 w1 = ((const float4*)(Wout + 256))[l5];
    int beg = off[n], end = off[n + 1];
    float di = dinv[n];

    f32x4 s = gather_accum_hw(hsb, csr, beg, end, l5);
    s += (f32x4){bflo(self.x), bfhi(self.x), bflo(self.y), bfhi(self.y)};

    float4 bb = ((const float4*)bias)[l5];
    float cx = fmaxf(fmaf(s.x, di, bb.x), 0.f);   // c1 chans (fp32)
    float cy = fmaxf(fmaf(s.y, di, bb.y), 0.f);
    float cz = fmaxf(fmaf(s.z, di, bb.z), 0.f);
    float cw = fmaxf(fmaf(s.w, di, bb.w), 0.f);

    float v = bflo(a.x) * wh.x + bfhi(a.x) * wh.y +
              bflo(a.y) * wh.z + bfhi(a.y) * wh.w +
              bflo(b2.x) * w0.x + bfhi(b2.x) * w0.y +
              bflo(b2.y) * w0.z + bfhi(b2.y) * w0.w +
              cx * w1.x + cy * w1.y + cz * w1.z + cw * w1.w;
#pragma unroll
    for (int o = 16; o; o >>= 1) v += __shfl_xor(v, o);  // stays within half
    if (l5 == 0) out[n] = v + bout[0];
}

// ---------------------------------------------------------------------------
extern "C" void kernel_launch(void* const* d_in, const int* in_sizes, int n_in,
                              void* d_out, int out_size, void* d_ws, size_t ws_size,
                              hipStream_t stream) {
    const float* x     = (const float*)d_in[0];
    const int*   eidx  = (const int*)d_in[1];
    const float* W_in  = (const float*)d_in[2];
    const float* b_in  = (const float*)d_in[3];
    const float* W_c0  = (const float*)d_in[4];
    const float* b_c0  = (const float*)d_in[5];
    const float* W_c1  = (const float*)d_in[6];
    const float* b_c1  = (const float*)d_in[7];
    const float* W_out = (const float*)d_in[8];
    const float* b_out = (const float*)d_in[9];
    float* out = (float*)d_out;

    const int* src = eidx;
    const int* dst = eidx + N_EDGES;

    // workspace layout (4-byte units)
    float*  ws     = (float*)d_ws;
    float*  dinv   = ws;                            // 100352
    int*    cnt    = (int*)(ws + 100352);           // 100352
    int*    off    = (int*)(ws + 200704);           // 100352 (N+1 used)
    int*    bsum   = (int*)(ws + 301056);           // 128
    int*    csr    = (int*)(ws + 301184);           // 1600000
    ushort* Wt_in  = (ushort*)(ws + 1901184);       // 32768 bf16
    ushort* Wt_c0  = (ushort*)(ws + 1917568);       // 16384 bf16
    ushort* Wt_c1  = (ushort*)(ws + 1925760);       // 16384 bf16
    ushort* h      = (ushort*)(ws + 1933952);       // 12.8M bf16
    ushort* c0     = (ushort*)(ws + 8333952);
    ushort* rank   = (ushort*)(ws + 14733952);      // 1.6M
    ushort* hs     = (ushort*)(ws + 21133952);

    // weight prep + cnt zero (one dispatch; must precede phase1)
    k_prep<<<354, 256, 0, stream>>>(W_in, W_c0, W_c1, Wt_in, Wt_c0, Wt_c1, cnt);

    // phase 1: input GEMM || count+rank (block-parity staggered)
    k_phase1<<<GB, 256, 0, stream>>>(x, Wt_in, b_in, h, dst, cnt, rank);

    // scan: cnt -> off, dinv  (B merged into C)
    k_scanA<<<SCAN_NB, 256, 0, stream>>>(cnt, bsum);
    k_scanC<<<SCAN_NB, 256, 0, stream>>>(cnt, bsum, off, dinv);

    // phase 3: conv0 GEMM || CSR fill (block-parity staggered)
    k_phase3<<<GB, 256, 0, stream>>>(h, Wt_c0, dinv, hs, src, dst, off, rank, csr);

    // conv0 aggregate (half-wave, 8 nodes/block)
    k_gather<<<M_NODES / 8, 256, 0, stream>>>(hs, csr, off, dinv, b_c0, c0);

    // conv1 GEMM
    k_gemm<128, 1, false><<<GB, 256, 0, stream>>>(c0, Wt_c1, nullptr, dinv, hs);

    // conv1 aggregate + output head (fused, half-wave)
    k_gather_out<<<M_NODES / 8, 256, 0, stream>>>(hs, csr, off, dinv, b_c1,
                                                  h, c0, W_out, b_out, out);
}